// Round 8
// baseline (328.064 us; speedup 1.0000x reference)
//
#include <hip/hip_runtime.h>
#include <hip/hip_bf16.h>

// Problem constants: B=256, N=128, EB=5, NA=64, DIM=512, NIT=3
// out = [logit (256 f32), graph_repr (256*512 f32)]

typedef __bf16 bf16;
typedef __bf16 bf16x4 __attribute__((ext_vector_type(4)));
typedef __bf16 bf16x8 __attribute__((ext_vector_type(8)));
typedef float floatx4 __attribute__((ext_vector_type(4)));

// HT: h^T [512 d][128 n], row stride exactly 128, 16B-chunk XOR swizzle:
//   phys element offset of logical n0 in row d = ((c ^ (d&15))<<3) + (n0&7), c = n0>>3.
//   b128 frag reads are bank-conflict-free (verified: each bank hit exactly 8x/wave).
#define TBS 40    // t row stride: 80 B (16B-multiple, 20-bank shift -> ~2-way, free)
#define AS  136   // AhatL row stride: 272 B (16B-multiple; read once)

// ---------------------------------------------------------------- merged weight transpose
// z<3: W_layers[z] (512x512) -> Wlb_t[z];  z==3: W_embed (64x512) -> Web_t
__global__ __launch_bounds__(256) void k_wt(const float* __restrict__ We,
                                            const float* __restrict__ Wl,
                                            bf16* __restrict__ WeT,
                                            bf16* __restrict__ WlT) {
    __shared__ bf16 tile[32][33];
    int z = blockIdx.z;
    const float* src;
    bf16* dst;
    int R;
    if (z < 3) { src = Wl + (size_t)z * 262144; dst = WlT + (size_t)z * 262144; R = 512; }
    else       { src = We;                      dst = WeT;                      R = 64; }
    int c0 = blockIdx.x * 32, r0 = blockIdx.y * 32;
    if (r0 >= R) return;
    int tx = threadIdx.x & 31, ty = threadIdx.x >> 5;
#pragma unroll
    for (int i = 0; i < 4; i++) {
        int r = ty + i * 8;
        tile[r][tx] = (bf16)src[(size_t)(r0 + r) * 512 + c0 + tx];
    }
    __syncthreads();
#pragma unroll
    for (int i = 0; i < 4; i++) {
        int c = ty + i * 8;
        dst[(size_t)(c0 + c) * R + r0 + tx] = tile[tx][c];
    }
}

// ---------------------------------------------------------------- fused WLS forward
// 1024 threads (16 waves, 4/SIMD), one block per batch. adj reduced to AhatL in a
// register-only prologue (r5's proven k_asum pattern, no cross-lane LDS);
// h^T lives in LDS for the whole kernel.
//
// pool: [0,131072) HT | [131072,141312) TB
//   prologue overlay at pool+0: AhatL 128 x AS bf16 (34816 B, dead before embed writes HT)
//   epilogue overlay in TB region: RsF[2][512] f32 + lpF[512] f32
__global__ __launch_bounds__(1024, 4) void k_mega(
    const float* __restrict__ adj,     // [256][128][128][5] f32
    const float* __restrict__ nodef,   // [256][128][64] f32
    const bf16* __restrict__ Web_t,    // [512][64]
    const float* __restrict__ b_embed, // [512]
    const bf16* __restrict__ Wlb_t,    // [3][512][512]
    const float* __restrict__ b_layers,// [3][512]
    const float* __restrict__ W_out,   // [512]
    const float* __restrict__ b_out,   // [1]
    float* __restrict__ out)           // [256 logit][256*512 graph_repr]
{
    __shared__ __align__(16) char pool[141312];
    bf16* HT = (bf16*)pool;
    bf16* TB = (bf16*)(pool + 131072);

    const int b = blockIdx.x;
    const int tid = threadIdx.x;
    const int lane = tid & 63, wid = tid >> 6;     // 16 waves
    const int q = lane >> 4, l16 = lane & 15;

    // ---------------- prologue: AhatL = sum_e adj[...,1:] + I  (register-only reduction;
    // thread owns 4 consecutive elements = 5 aligned float4 loads, as r5's k_asum)
    bf16* AhatL = (bf16*)pool;                     // [128][AS]
    {
        const float4* srcb = (const float4*)(adj + (size_t)b * 81920);
#pragma unroll
        for (int p = 0; p < 4; p++) {
            int t = p * 1024 + tid;                // 4-element group id, 0..4095
            const float4* ptr = srcb + (size_t)t * 5;
            float4 v0 = ptr[0], v1 = ptr[1], v2 = ptr[2], v3 = ptr[3], v4 = ptr[4];
            float s0 = v0.y + v0.z + v0.w + v1.x;
            float s1 = v1.z + v1.w + v2.x + v2.y;
            float s2 = v2.w + v3.x + v3.y + v3.z;
            float s3 = v4.x + v4.y + v4.z + v4.w;
            int n = t >> 5, m0 = (t & 31) * 4;
            bf16x4 o;
            o[0] = (bf16)(s0 + ((n == m0 + 0) ? 1.f : 0.f));
            o[1] = (bf16)(s1 + ((n == m0 + 1) ? 1.f : 0.f));
            o[2] = (bf16)(s2 + ((n == m0 + 2) ? 1.f : 0.f));
            o[3] = (bf16)(s3 + ((n == m0 + 3) ? 1.f : 0.f));
            *(bf16x4*)&AhatL[n * AS + m0] = o;
        }
    }
    __syncthreads();

    // Ahat B-frags, register-resident for all 3 iterations (ph1 roles: dt x ntw = 2 x 8)
    const int dt = wid >> 3, ntw = wid & 7;
    bf16x8 ahf[4];
#pragma unroll
    for (int kk = 0; kk < 4; kk++)
        ahf[kk] = *(const bf16x8*)&AhatL[(ntw * 16 + l16) * AS + kk * 32 + q * 8];
    __syncthreads();   // AhatL dead; HT region may be written now

    // ---------------- embed: HT = (node @ W_embed + b_embed)^T  (wave grid 2 x 8)
    {
        const int wmE = wid >> 3, wnE = wid & 7;
        const float* Ab = nodef + (size_t)b * 8192;
        floatx4 accE[4][4] = {};
#pragma unroll
        for (int kk = 0; kk < 2; kk++) {
            bf16x8 af[4], bfr[4];
#pragma unroll
            for (int mt = 0; mt < 4; mt++) {
                const float* srcp = Ab + (size_t)(wmE * 64 + mt * 16 + l16) * 64 + kk * 32 + q * 8;
                float4 x = *(const float4*)srcp;
                float4 y = *(const float4*)(srcp + 4);
                bf16x8 v;
                v[0] = (bf16)x.x; v[1] = (bf16)x.y; v[2] = (bf16)x.z; v[3] = (bf16)x.w;
                v[4] = (bf16)y.x; v[5] = (bf16)y.y; v[6] = (bf16)y.z; v[7] = (bf16)y.w;
                af[mt] = v;
            }
#pragma unroll
            for (int nt = 0; nt < 4; nt++)
                bfr[nt] = *(const bf16x8*)(Web_t + (size_t)(wnE * 64 + nt * 16 + l16) * 64 + kk * 32 + q * 8);
#pragma unroll
            for (int mt = 0; mt < 4; mt++)
#pragma unroll
                for (int nt = 0; nt < 4; nt++)
                    accE[mt][nt] = __builtin_amdgcn_mfma_f32_16x16x32_bf16(af[mt], bfr[nt], accE[mt][nt], 0, 0, 0);
        }
#pragma unroll
        for (int mt = 0; mt < 4; mt++)
#pragma unroll
            for (int nt = 0; nt < 4; nt++) {
                int d = wnE * 64 + nt * 16 + l16;
                float bv = b_embed[d];
                int c = wmE * 8 + mt * 2 + (q >> 1);        // 16B chunk of n0
                int off = ((c ^ (d & 15)) << 3) + (q & 1) * 4;
                bf16x4 pk;
#pragma unroll
                for (int r = 0; r < 4; r++) pk[r] = (bf16)(accE[mt][nt][r] + bv);
                *(bf16x4*)&HT[d * 128 + off] = pk;
            }
    }
    __syncthreads();

    // ph2 roles: nw (n-half) x dw (64-wide d'-slice) = 2 x 8
    const int nw = wid & 1, dw = wid >> 1;

    // ---------------- 3 WLS iterations
    for (int it = 0; it < 3; it++) {
        const bf16* WT = Wlb_t + (size_t)it * 262144;
        const float* bl = b_layers + it * 512;
        floatx4 acc[4][4] = {};   // [mt: n][nt: d']

        for (int dc = 0; dc < 16; dc++) {
            // prefetch ph2 W-frags (global, fly during ph1; drained by the barrier)
            bf16x8 bfr[4];
#pragma unroll
            for (int nt = 0; nt < 4; nt++)
                bfr[nt] = *(const bf16x8*)(WT + (size_t)(dw * 64 + nt * 16 + l16) * 512 + dc * 32 + q * 8);

            // ----- ph1: t^T[dc] -> TB (one 16x16 tile per wave)
            floatx4 a1 = {};
            {
                int drow = dc * 32 + dt * 16 + l16;
#pragma unroll
                for (int kk = 0; kk < 4; kk++) {
                    int off = ((4 * kk + q) ^ (drow & 15)) << 3;
                    bf16x8 af = *(const bf16x8*)&HT[drow * 128 + off];
                    a1 = __builtin_amdgcn_mfma_f32_16x16x32_bf16(af, ahf[kk], a1, 0, 0, 0);
                }
            }
            {
                bf16x4 pk;
#pragma unroll
                for (int r = 0; r < 4; r++) pk[r] = (bf16)a1[r];
                *(bf16x4*)&TB[(ntw * 16 + l16) * TBS + dt * 16 + q * 4] = pk;
            }
            __syncthreads();

            // ----- ph2: acc += t[dc] @ W[dc]  (wave tile 64n x 64d')
            bf16x8 af2[4];
#pragma unroll
            for (int mt = 0; mt < 4; mt++)
                af2[mt] = *(const bf16x8*)&TB[(nw * 64 + mt * 16 + l16) * TBS + q * 8];
#pragma unroll
            for (int nt = 0; nt < 4; nt++)
#pragma unroll
                for (int mt = 0; mt < 4; mt++)
                    acc[mt][nt] = __builtin_amdgcn_mfma_f32_16x16x32_bf16(af2[mt], bfr[nt], acc[mt][nt], 0, 0, 0);
            __syncthreads();
        }

        if (it < 2) {
            // h'^T = relu(acc + bias) -> HT (swizzled)
#pragma unroll
            for (int nt = 0; nt < 4; nt++) {
                int dp = dw * 64 + nt * 16 + l16;
                float bv = bl[dp];
#pragma unroll
                for (int mt = 0; mt < 4; mt++) {
                    int c = nw * 8 + mt * 2 + (q >> 1);
                    int off = ((c ^ (dp & 15)) << 3) + (q & 1) * 4;
                    bf16x4 pk;
#pragma unroll
                    for (int r = 0; r < 4; r++) pk[r] = (bf16)fmaxf(acc[mt][nt][r] + bv, 0.f);
                    *(bf16x4*)&HT[dp * 128 + off] = pk;
                }
            }
            __syncthreads();
        } else {
            // fused mean over the wave's 64 n-rows
            float* RsF = (float*)(pool + 131072);   // [2][512]
#pragma unroll
            for (int nt = 0; nt < 4; nt++) {
                int dp = dw * 64 + nt * 16 + l16;
                float bv = bl[dp];
                float s = 0.f;
#pragma unroll
                for (int mt = 0; mt < 4; mt++)
#pragma unroll
                    for (int r = 0; r < 4; r++)
                        s += fmaxf(acc[mt][nt][r] + bv, 0.f);
                s += __shfl_down(s, 32);
                s += __shfl_down(s, 16);
                if (lane < 16) RsF[nw * 512 + dp] = s;
            }
        }
    }
    __syncthreads();

    // ---------------- finalize: graph_repr + logit
    float* RsF = (float*)(pool + 131072);
    float* lpF = (float*)(pool + 131072 + 4096);
    if (tid < 512) {
        float g = (RsF[tid] + RsF[512 + tid]) * (1.f / 128.f);
        out[256 + (size_t)b * 512 + tid] = g;
        lpF[tid] = g * W_out[tid];
    }
    __syncthreads();
    for (int s = 256; s > 0; s >>= 1) {
        if (tid < s) lpF[tid] += lpF[tid + s];
        __syncthreads();
    }
    if (tid == 0) out[b] = lpF[0] + b_out[0];
}

// ---------------------------------------------------------------- launch
extern "C" void kernel_launch(void* const* d_in, const int* in_sizes, int n_in,
                              void* d_out, int out_size, void* d_ws, size_t ws_size,
                              hipStream_t stream) {
    const float* adj      = (const float*)d_in[0];
    // d_in[1] = hidden (unused by forward)
    const float* node     = (const float*)d_in[2];
    const float* W_embed  = (const float*)d_in[3];
    const float* b_embed  = (const float*)d_in[4];
    const float* W_layers = (const float*)d_in[5];
    const float* b_layers = (const float*)d_in[6];
    const float* W_out    = (const float*)d_in[7];
    const float* b_out    = (const float*)d_in[8];
    float* out = (float*)d_out;

    char* ws = (char*)d_ws;
    bf16* Web_t = (bf16*)(ws);              //     65,536 B : W_embed^T bf16 [512][64]
    bf16* Wlb_t = (bf16*)(ws + 65536);      //  1,572,864 B : W_layers^T bf16 [3][512][512] (end 1.6 MB)

    k_wt<<<dim3(16, 16, 4), 256, 0, stream>>>(W_embed, W_layers, Web_t, Wlb_t);
    k_mega<<<256, 1024, 0, stream>>>(adj, node, Web_t, b_embed, Wlb_t, b_layers,
                                     W_out, b_out, out);
}

// Round 9
// 261.976 us; speedup vs baseline: 1.2523x; 1.2523x over previous
//
#include <hip/hip_runtime.h>
#include <hip/hip_bf16.h>

// Problem constants: B=256, N=128, EB=5, NA=64, DIM=512, NIT=3
// out = [logit (256 f32), graph_repr (256*512 f32)]

typedef __bf16 bf16;
typedef __bf16 bf16x4 __attribute__((ext_vector_type(4)));
typedef __bf16 bf16x8 __attribute__((ext_vector_type(8)));
typedef float floatx4 __attribute__((ext_vector_type(4)));

// HT: h^T [512 d][128 n], row stride exactly 128, 16B-chunk XOR swizzle:
//   phys element offset of logical n0 in row d = ((c ^ (d&15))<<3) + (n0&7), c = n0>>3.
#define TBS 40    // t row stride: 80 B (16B-multiple, 20-bank shift -> ~2-way, free)
#define AS  136   // AhatL row stride: 272 B (16B-multiple; read once)

// ---------------------------------------------------------------- pack W into MFMA B-fragment order
// src f32 [K][512] -> dst bf16: dst[((td*(K/32)+tk)*64 + lane)*8 + j]
//   = src[tk*32 + (lane>>4)*8 + j][td*16 + (lane&15)]
// so a wave's B-frag load for (d'-tile td, k-chunk tk) is one contiguous 1 KB read.
// grid: (td=32, z=4): z<3 -> W_layers[z] (K=512); z==3 -> W_embed (K=64)
__global__ __launch_bounds__(256) void k_pack(const float* __restrict__ We,
                                              const float* __restrict__ Wl,
                                              bf16* __restrict__ PWe,
                                              bf16* __restrict__ PWl) {
    __shared__ float S[512][17];
    int z = blockIdx.y, td = blockIdx.x;
    const float* src; bf16* dst; int K;
    if (z < 3) { src = Wl + (size_t)z * 262144; dst = PWl + (size_t)z * 262144; K = 512; }
    else       { src = We;                      dst = PWe;                      K = 64; }
    int tid = threadIdx.x;
    int x = tid & 15, y = tid >> 4;
    for (int kb = 0; kb < K; kb += 16) {
        int k = kb + y;
        S[k][x] = src[(size_t)k * 512 + td * 16 + x];
    }
    __syncthreads();
    int lane = tid & 63, w = tid >> 6, q = lane >> 4, l16 = lane & 15;
    int KT = K >> 5;
    for (int tk = w; tk < KT; tk += 4) {
        bf16x8 v;
#pragma unroll
        for (int j = 0; j < 8; j++) v[j] = (bf16)S[tk * 32 + q * 8 + j][l16];
        *(bf16x8*)&dst[(size_t)((td * KT + tk) * 64 + lane) * 8] = v;
    }
}

// ---------------------------------------------------------------- fused WLS forward
// 1024 threads (16 waves, 4/SIMD), one block per batch. Register-budget rule: a 16-wave
// block needs <=128 VGPR/wave (4 waves/SIMD) — keep max-live under that everywhere.
//
// pool: [0,131072) HT | [131072,141312) TB
//   prologue overlay at pool+0: AhatL 128 x AS bf16 (dead before embed writes HT)
//   epilogue overlay in TB region: RsF[2][512] f32 + lpF[512] f32
__global__ __launch_bounds__(1024, 4) void k_mega(
    const float* __restrict__ adj,     // [256][128][128][5] f32
    const float* __restrict__ nodef,   // [256][128][64] f32
    const bf16* __restrict__ PWe,      // packed W_embed frags
    const float* __restrict__ b_embed, // [512]
    const bf16* __restrict__ PWl,      // packed W_layers frags [3][...]
    const float* __restrict__ b_layers,// [3][512]
    const float* __restrict__ W_out,   // [512]
    const float* __restrict__ b_out,   // [1]
    float* __restrict__ out)           // [256 logit][256*512 graph_repr]
{
    __shared__ __align__(16) char pool[141312];
    bf16* HT = (bf16*)pool;
    bf16* TB = (bf16*)(pool + 131072);

    const int b = blockIdx.x;
    const int tid = threadIdx.x;
    const int lane = tid & 63, wid = tid >> 6;     // 16 waves
    const int q = lane >> 4, l16 = lane & 15;

    // ---------------- prologue: AhatL = sum_e adj[...,1:] + I (register-only reduction)
    bf16* AhatL = (bf16*)pool;                     // [128][AS]
    {
        const float4* srcb = (const float4*)(adj + (size_t)b * 81920);
#pragma unroll 2
        for (int p = 0; p < 4; p++) {
            int t = p * 1024 + tid;                // 4-element group id, 0..4095
            const float4* ptr = srcb + (size_t)t * 5;
            float4 v0 = ptr[0], v1 = ptr[1], v2 = ptr[2], v3 = ptr[3], v4 = ptr[4];
            float s0 = v0.y + v0.z + v0.w + v1.x;
            float s1 = v1.z + v1.w + v2.x + v2.y;
            float s2 = v2.w + v3.x + v3.y + v3.z;
            float s3 = v4.x + v4.y + v4.z + v4.w;
            int n = t >> 5, m0 = (t & 31) * 4;
            bf16x4 o;
            o[0] = (bf16)(s0 + ((n == m0 + 0) ? 1.f : 0.f));
            o[1] = (bf16)(s1 + ((n == m0 + 1) ? 1.f : 0.f));
            o[2] = (bf16)(s2 + ((n == m0 + 2) ? 1.f : 0.f));
            o[3] = (bf16)(s3 + ((n == m0 + 3) ? 1.f : 0.f));
            *(bf16x4*)&AhatL[n * AS + m0] = o;
        }
    }
    __syncthreads();

    // Ahat B-frags, register-resident for all 3 iterations (ph1 roles: dt x ntw = 2 x 8)
    const int dt = wid >> 3, ntw = wid & 7;
    bf16x8 ahf[4];
#pragma unroll
    for (int kk = 0; kk < 4; kk++)
        ahf[kk] = *(const bf16x8*)&AhatL[(ntw * 16 + l16) * AS + kk * 32 + q * 8];
    __syncthreads();   // AhatL dead; HT region may be written now

    // ---------------- embed: HT = (node @ W_embed + b_embed)^T  (wave grid 2 x 8)
    {
        const int wmE = wid >> 3, wnE = wid & 7;
        const float* Ab = nodef + (size_t)b * 8192;
        floatx4 accE[4][4] = {};
#pragma unroll
        for (int kk = 0; kk < 2; kk++) {
            bf16x8 af[4], bfr[4];
#pragma unroll
            for (int mt = 0; mt < 4; mt++) {
                const float* srcp = Ab + (size_t)(wmE * 64 + mt * 16 + l16) * 64 + kk * 32 + q * 8;
                float4 x = *(const float4*)srcp;
                float4 y = *(const float4*)(srcp + 4);
                bf16x8 v;
                v[0] = (bf16)x.x; v[1] = (bf16)x.y; v[2] = (bf16)x.z; v[3] = (bf16)x.w;
                v[4] = (bf16)y.x; v[5] = (bf16)y.y; v[6] = (bf16)y.z; v[7] = (bf16)y.w;
                af[mt] = v;
            }
#pragma unroll
            for (int nt = 0; nt < 4; nt++) {
                int td = wnE * 4 + nt;             // 16-wide d tile
                bfr[nt] = *(const bf16x8*)&PWe[(size_t)((td * 2 + kk) * 64 + lane) * 8];
            }
#pragma unroll
            for (int mt = 0; mt < 4; mt++)
#pragma unroll
                for (int nt = 0; nt < 4; nt++)
                    accE[mt][nt] = __builtin_amdgcn_mfma_f32_16x16x32_bf16(af[mt], bfr[nt], accE[mt][nt], 0, 0, 0);
        }
#pragma unroll
        for (int mt = 0; mt < 4; mt++)
#pragma unroll
            for (int nt = 0; nt < 4; nt++) {
                int d = wnE * 64 + nt * 16 + l16;
                float bv = b_embed[d];
                int c = wmE * 8 + mt * 2 + (q >> 1);        // 16B chunk of n0
                int off = ((c ^ (d & 15)) << 3) + (q & 1) * 4;
                bf16x4 pk;
#pragma unroll
                for (int r = 0; r < 4; r++) pk[r] = (bf16)(accE[mt][nt][r] + bv);
                *(bf16x4*)&HT[d * 128 + off] = pk;
            }
    }
    __syncthreads();

    // ph2 roles: nw (n-half) x dw (64-wide d'-slice) = 2 x 8
    const int nw = wid & 1, dw = wid >> 1;

    // ---------------- 3 WLS iterations
    for (int it = 0; it < 3; it++) {
        const bf16* WT = PWl + (size_t)it * 262144;
        const float* bl = b_layers + it * 512;
        floatx4 acc[4][4] = {};   // [mt: n][nt: d']

        for (int dc = 0; dc < 16; dc++) {
            // prefetch first two ph2 W-frags (contiguous 1 KB wave loads; fly during ph1)
            bf16x8 bfr0 = *(const bf16x8*)&WT[(size_t)(((dw * 4 + 0) * 16 + dc) * 64 + lane) * 8];
            bf16x8 bfr1 = *(const bf16x8*)&WT[(size_t)(((dw * 4 + 1) * 16 + dc) * 64 + lane) * 8];

            // ----- ph1: t^T[dc] -> TB (one 16x16 tile per wave)
            floatx4 a1 = {};
            {
                int drow = dc * 32 + dt * 16 + l16;
#pragma unroll
                for (int kk = 0; kk < 4; kk++) {
                    int off = ((4 * kk + q) ^ (drow & 15)) << 3;
                    bf16x8 af = *(const bf16x8*)&HT[drow * 128 + off];
                    a1 = __builtin_amdgcn_mfma_f32_16x16x32_bf16(af, ahf[kk], a1, 0, 0, 0);
                }
            }
            {
                bf16x4 pk;
#pragma unroll
                for (int r = 0; r < 4; r++) pk[r] = (bf16)a1[r];
                *(bf16x4*)&TB[(ntw * 16 + l16) * TBS + dt * 16 + q * 4] = pk;
            }
            __syncthreads();

            // ----- ph2: acc += t[dc] @ W[dc]  (wave tile 64n x 64d', staggered B loads)
            bf16x8 af2[4];
#pragma unroll
            for (int mt = 0; mt < 4; mt++)
                af2[mt] = *(const bf16x8*)&TB[(nw * 64 + mt * 16 + l16) * TBS + q * 8];
            bf16x8 bfr2 = *(const bf16x8*)&WT[(size_t)(((dw * 4 + 2) * 16 + dc) * 64 + lane) * 8];
#pragma unroll
            for (int mt = 0; mt < 4; mt++)
                acc[mt][0] = __builtin_amdgcn_mfma_f32_16x16x32_bf16(af2[mt], bfr0, acc[mt][0], 0, 0, 0);
            bf16x8 bfr3 = *(const bf16x8*)&WT[(size_t)(((dw * 4 + 3) * 16 + dc) * 64 + lane) * 8];
#pragma unroll
            for (int mt = 0; mt < 4; mt++)
                acc[mt][1] = __builtin_amdgcn_mfma_f32_16x16x32_bf16(af2[mt], bfr1, acc[mt][1], 0, 0, 0);
#pragma unroll
            for (int mt = 0; mt < 4; mt++)
                acc[mt][2] = __builtin_amdgcn_mfma_f32_16x16x32_bf16(af2[mt], bfr2, acc[mt][2], 0, 0, 0);
#pragma unroll
            for (int mt = 0; mt < 4; mt++)
                acc[mt][3] = __builtin_amdgcn_mfma_f32_16x16x32_bf16(af2[mt], bfr3, acc[mt][3], 0, 0, 0);
            __syncthreads();
        }

        if (it < 2) {
            // h'^T = relu(acc + bias) -> HT (swizzled)
#pragma unroll
            for (int nt = 0; nt < 4; nt++) {
                int dp = dw * 64 + nt * 16 + l16;
                float bv = bl[dp];
#pragma unroll
                for (int mt = 0; mt < 4; mt++) {
                    int c = nw * 8 + mt * 2 + (q >> 1);
                    int off = ((c ^ (dp & 15)) << 3) + (q & 1) * 4;
                    bf16x4 pk;
#pragma unroll
                    for (int r = 0; r < 4; r++) pk[r] = (bf16)fmaxf(acc[mt][nt][r] + bv, 0.f);
                    *(bf16x4*)&HT[dp * 128 + off] = pk;
                }
            }
            __syncthreads();
        } else {
            // fused mean over the wave's 64 n-rows
            float* RsF = (float*)(pool + 131072);   // [2][512]
#pragma unroll
            for (int nt = 0; nt < 4; nt++) {
                int dp = dw * 64 + nt * 16 + l16;
                float bv = bl[dp];
                float s = 0.f;
#pragma unroll
                for (int mt = 0; mt < 4; mt++)
#pragma unroll
                    for (int r = 0; r < 4; r++)
                        s += fmaxf(acc[mt][nt][r] + bv, 0.f);
                s += __shfl_down(s, 32);
                s += __shfl_down(s, 16);
                if (lane < 16) RsF[nw * 512 + dp] = s;
            }
        }
    }
    __syncthreads();

    // ---------------- finalize: graph_repr + logit
    float* RsF = (float*)(pool + 131072);
    float* lpF = (float*)(pool + 131072 + 4096);
    if (tid < 512) {
        float g = (RsF[tid] + RsF[512 + tid]) * (1.f / 128.f);
        out[256 + (size_t)b * 512 + tid] = g;
        lpF[tid] = g * W_out[tid];
    }
    __syncthreads();
    for (int s = 256; s > 0; s >>= 1) {
        if (tid < s) lpF[tid] += lpF[tid + s];
        __syncthreads();
    }
    if (tid == 0) out[b] = lpF[0] + b_out[0];
}

// ---------------------------------------------------------------- launch
extern "C" void kernel_launch(void* const* d_in, const int* in_sizes, int n_in,
                              void* d_out, int out_size, void* d_ws, size_t ws_size,
                              hipStream_t stream) {
    const float* adj      = (const float*)d_in[0];
    // d_in[1] = hidden (unused by forward)
    const float* node     = (const float*)d_in[2];
    const float* W_embed  = (const float*)d_in[3];
    const float* b_embed  = (const float*)d_in[4];
    const float* W_layers = (const float*)d_in[5];
    const float* b_layers = (const float*)d_in[6];
    const float* W_out    = (const float*)d_in[7];
    const float* b_out    = (const float*)d_in[8];
    float* out = (float*)d_out;

    char* ws = (char*)d_ws;
    bf16* PWe = (bf16*)(ws);              //     65,536 B : packed W_embed frags
    bf16* PWl = (bf16*)(ws + 65536);      //  1,572,864 B : packed W_layers frags (end 1.6 MB)

    k_pack<<<dim3(32, 4), 256, 0, stream>>>(W_embed, W_layers, PWe, PWl);
    k_mega<<<256, 1024, 0, stream>>>(adj, node, PWe, b_embed, PWl, b_layers,
                                     W_out, b_out, out);
}